// Round 8
// baseline (516.044 us; speedup 1.0000x reference)
//
#include <hip/hip_runtime.h>
#include <math.h>
#include <stdint.h>

#define NG 8
#define GS 2048
#define DM 512
#define NE 64
#define CAP 32
#define NROWS (NG * GS)                       // 16384 total rows (g,s)
#define COMBINE_ELEMS (33554432ull)           // 8*2048*64*32

#define N4 16777216                           // 268435456 B / 16
#define GRID_BLKS 4096                        // 256 gate + 3840 zero
#define ZERO_BLOCKS 3840
#define TBS 21                                // transpose buffer stride (odd)

typedef float f32x4 __attribute__((ext_vector_type(4)));
typedef double f64x4 __attribute__((ext_vector_type(4)));

// ---------------------------------------------------------------------------
// JAX Threefry-2x32 (partitionable path).  [verified: rounds 1,3,4,5,7]
// ---------------------------------------------------------------------------
__device__ __forceinline__ void threefry2x32(uint32_t k0, uint32_t k1,
                                             uint32_t x0, uint32_t x1,
                                             uint32_t& o0, uint32_t& o1) {
  uint32_t ks[3] = {k0, k1, k0 ^ k1 ^ 0x1BD11BDAu};
  x0 += ks[0];
  x1 += ks[1];
  const uint32_t rot[2][4] = {{13u, 15u, 26u, 6u}, {17u, 29u, 16u, 24u}};
#pragma unroll
  for (int i = 0; i < 5; ++i) {
#pragma unroll
    for (int j = 0; j < 4; ++j) {
      uint32_t r = rot[i & 1][j];
      x0 += x1;
      x1 = (x1 << r) | (x1 >> (32u - r));
      x1 ^= x0;
    }
    x0 += ks[(i + 1) % 3];
    x1 += ks[(i + 2) % 3] + (uint32_t)(i + 1);
  }
  o0 = x0;
  o1 = x1;
}

// XLA ErfInv (f32), Giles polynomial — constants bit-match xla math.cc.
__device__ __forceinline__ float erfinv_xla(float x) {
  float w = -log1pf(-x * x);
  float p;
  if (w < 5.0f) {
    w = w - 2.5f;
    p = 2.81022636e-08f;
    p = __fmaf_rn(p, w, 3.43273939e-07f);
    p = __fmaf_rn(p, w, -3.5233877e-06f);
    p = __fmaf_rn(p, w, -4.39150654e-06f);
    p = __fmaf_rn(p, w, 0.00021858087f);
    p = __fmaf_rn(p, w, -0.00125372503f);
    p = __fmaf_rn(p, w, -0.00417768164f);
    p = __fmaf_rn(p, w, 0.246640727f);
    p = __fmaf_rn(p, w, 1.50140941f);
  } else {
    w = sqrtf(w) - 3.0f;
    p = -0.000200214257f;
    p = __fmaf_rn(p, w, 0.000100950558f);
    p = __fmaf_rn(p, w, 0.00134934322f);
    p = __fmaf_rn(p, w, -0.00367342844f);
    p = __fmaf_rn(p, w, 0.00573950773f);
    p = __fmaf_rn(p, w, -0.0076224613f);
    p = __fmaf_rn(p, w, 0.00943887047f);
    p = __fmaf_rn(p, w, 1.00167406f);
    p = __fmaf_rn(p, w, 2.83297682f);
  }
  return p * x;
}

__device__ __forceinline__ float jax_normal(uint32_t idx) {
  uint32_t o0, o1;
  threefry2x32(0u, 42u, 0u, idx, o0, o1);
  uint32_t bits = o0 ^ o1;
  float f = __uint_as_float((bits >> 9) | 0x3f800000u) - 1.0f;  // [0,1)
  const float lo = __uint_as_float(0xBF7FFFFFu);                // -0.99999994
  float v = fmaxf(lo, f * 2.0f + lo);
  return __uint_as_float(0x3FB504F3u) * erfinv_xla(v);  // sqrt(2)_f32 * erfinv
}

// ---------------------------------------------------------------------------
// Fused kernel, 4096 blocks: bid%16==0 -> gate (256), else zero (3840).
// LDS = 21.5 KB (transpose buffer only) and VGPR<=128 via launch_bounds
// -> 4 blocks/CU = 16 waves/CU so the zero stream saturates HBM writes
// (round-7 lesson: 128KB LDS starved zeroing at 1 block/CU).
// Gate: no x-staging; A operand read per-lane from global (4 independent
// MFMA accumulator chains hide the latency), mapping discovered by the
// runtime marker-MFMA probe [verified round 7].
// ---------------------------------------------------------------------------
__global__ __launch_bounds__(256, 4) void fused_kernel(
    const float* __restrict__ x,    // (NROWS, 512)
    const float* __restrict__ Wt,   // (512, 64)
    float* __restrict__ gatesT,     // (NG*NE, GS)
    f32x4* __restrict__ outv) {     // output as f32x4[N4]
  __shared__ float tb_all[4][NE * TBS];   // 4 waves x 64 experts x 21 words
  const int bid = blockIdx.x;

  if (bid & 15) {
    // ---- zero block ----
    const int zid = bid - (bid >> 4) - 1;   // 0..ZERO_BLOCKS-1
    const f32x4 z = {0.f, 0.f, 0.f, 0.f};
    for (int i = zid * 256 + threadIdx.x; i < N4; i += ZERO_BLOCKS * 256)
      __builtin_nontemporal_store(z, &outv[i]);
    return;
  }

  // ---- gate block ----
  const int gid = bid >> 4;           // 0..255
  const int tid = threadIdx.x;
  const int l = tid & 63;             // lane
  const int w = tid >> 6;             // wave 0..3
  const int row0 = gid * 64 + w * 16; // wave's first row

  const int i15 = l & 15;             // A row / B-C col position
  const int k4 = l >> 4;              // k-slot within K=4

  // --- runtime probe: which x-row does acc[*][r] hold?  [verified round 7]
  f64x4 dr = {0., 0., 0., 0.};
  dr = __builtin_amdgcn_mfma_f64_16x16x4f64((double)i15, 0.25, dr, 0, 0, 0);
  int perm[4];
#pragma unroll
  for (int r = 0; r < 4; ++r) perm[r] = ((int)(dr[r] + 0.5)) & 15;

  // K-loop: 128 steps of K=4; acc[t] = 16x16 tile for experts 16t..16t+15.
  // A element straight from global: x[(row0+i15)*512 + kk*4 + k4].
  const float* xl = x + (size_t)(row0 + i15) * DM + k4;
  const float* wl = Wt + k4 * NE + i15;
  f64x4 acc[4] = {{0., 0., 0., 0.}, {0., 0., 0., 0.},
                  {0., 0., 0., 0.}, {0., 0., 0., 0.}};
#pragma unroll 4
  for (int kk = 0; kk < 128; ++kk) {
    const double a = (double)xl[kk * 4];
    const float* wrow = wl + kk * 4 * NE;
#pragma unroll
    for (int t = 0; t < 4; ++t) {
      const double b = (double)wrow[16 * t];
      acc[t] = __builtin_amdgcn_mfma_f64_16x16x4f64(a, b, acc[t], 0, 0, 0);
    }
  }

  // noise + fp64 softmax. acc[t][r] = logits[row0+perm[r]][e=16t+i15].
  // 16-lane shfl_xor reduce spans that row's 64 experts (16 lanes x 4 regs).
  float gatef[4][4];  // [t][r]
#pragma unroll
  for (int r = 0; r < 4; ++r) {
    const int row = row0 + perm[r];
    double v[4];
    double m = -1.0e300;
#pragma unroll
    for (int t = 0; t < 4; ++t) {
      const float logit = (float)acc[t][r];
      const float noised =
          logit + 0.015625f * jax_normal((uint32_t)(row * NE + 16 * t + i15));
      v[t] = (double)noised;
      m = fmax(m, v[t]);
    }
#pragma unroll
    for (int off = 1; off < 16; off <<= 1) m = fmax(m, __shfl_xor(m, off, 64));
    double s = 0.0;
#pragma unroll
    for (int t = 0; t < 4; ++t) {
      v[t] = exp(v[t] - m);
      s += v[t];
    }
#pragma unroll
    for (int off = 1; off < 16; off <<= 1) s += __shfl_xor(s, off, 64);
#pragma unroll
    for (int t = 0; t < 4; ++t) gatef[t][r] = (float)(v[t] / s);
  }

  // per-wave LDS transpose -> coalesced 16B gatesT stores.
  float* tb = tb_all[w];
#pragma unroll
  for (int t = 0; t < 4; ++t)
#pragma unroll
    for (int r = 0; r < 4; ++r)
      tb[(16 * t + i15) * TBS + perm[r]] = gatef[t][r];
  __syncthreads();

  const int g = row0 >> 11;           // group
  const int s0 = row0 & (GS - 1);     // first s of this wave's 16
  float* drow = gatesT + ((size_t)(g * NE + l)) * GS + s0;  // lane l -> expert l
#pragma unroll
  for (int c = 0; c < 4; ++c) {
    f32x4 o;
#pragma unroll
    for (int i = 0; i < 4; ++i) o[i] = tb[l * TBS + 4 * c + i];  // scalar ds_read, conflict-free (stride 21)
    *(f32x4*)&drow[4 * c] = o;
  }
}

// ---------------------------------------------------------------------------
// Topk: one WAVE per (group, expert); 8 coalesced f32x4 loads/lane; top-32
// via per-lane scan + shfl_xor butterfly (max value, min s on ties).
// [verified: rounds 4,5,7]
// ---------------------------------------------------------------------------
__global__ __launch_bounds__(64) void topk_kernel(
    const float* __restrict__ gatesT,  // (NG*NE, GS)
    float* __restrict__ out) {         // combine ++ dispatch
  const int ge = blockIdx.x;  // == g*64 + e
  const int g = ge >> 6;
  const int e = ge & 63;
  const int lane = threadIdx.x;

  const float* base = gatesT + (size_t)ge * GS;
  float v[32];
#pragma unroll
  for (int k = 0; k < 8; ++k) {
    const f32x4 t = *(const f32x4*)(base + k * 256 + lane * 4);
#pragma unroll
    for (int i = 0; i < 4; ++i) v[k * 4 + i] = t[i];
  }

  float my_v = 0.0f;
  int my_s = 0;

  for (int c = 0; c < CAP; ++c) {
    float bv = -1.0f;  // gates are strictly positive
    int bj = 0;
#pragma unroll
    for (int j = 0; j < 32; ++j) {
      const bool better = v[j] > bv;
      bv = better ? v[j] : bv;
      bj = better ? j : bj;
    }
    int bs = (bj >> 2) * 256 + lane * 4 + (bj & 3);
#pragma unroll
    for (int off = 1; off < 64; off <<= 1) {
      const float ov = __shfl_xor(bv, off, 64);
      const int os = __shfl_xor(bs, off, 64);
      if (ov > bv || (ov == bv && os < bs)) { bv = ov; bs = os; }
    }
    const bool owner = (lane == ((bs >> 2) & 63));
    const int jj = ((bs >> 8) << 2) | (bs & 3);
#pragma unroll
    for (int j = 0; j < 32; ++j) v[j] = (owner && j == jj) ? -1.0f : v[j];
    if (lane == c) { my_v = bv; my_s = bs; }
  }

  float* combine = out;                   // (G,S,E,C)
  float* dispatch = out + COMBINE_ELEMS;  // (G,E,C,S)
  if (lane < CAP) {
    combine[(((size_t)(g * GS + my_s)) * NE + e) * CAP + lane] = my_v;
    dispatch[(((size_t)(g * NE + e)) * CAP + lane) * GS + my_s] = 1.0f;
  }
}

extern "C" void kernel_launch(void* const* d_in, const int* in_sizes, int n_in,
                              void* d_out, int out_size, void* d_ws,
                              size_t ws_size, hipStream_t stream) {
  (void)in_sizes; (void)n_in; (void)ws_size; (void)out_size;
  const float* x = (const float*)d_in[0];   // (8,2048,512) f32
  const float* Wt = (const float*)d_in[1];  // (512,64) f32
  float* out = (float*)d_out;
  float* gatesT = (float*)d_ws;             // (512, 2048) f32 = 4 MB scratch

  fused_kernel<<<GRID_BLKS, 256, 0, stream>>>(x, Wt, gatesT, (f32x4*)out);
  topk_kernel<<<NG * NE, 64, 0, stream>>>(gatesT, out);
}

// Round 9
// 173.166 us; speedup vs baseline: 2.9801x; 2.9801x over previous
//
#include <hip/hip_runtime.h>
#include <math.h>
#include <stdint.h>

#define NG 8
#define GS 2048
#define DM 512
#define NE 64
#define CAP 32
#define NROWS (NG * GS)                       // 16384 total rows (g,s)
#define COMBINE_ELEMS (33554432ull)           // 8*2048*64*32

#define ZERO_BLOCKS 2048
#define GATE_BLOCKS 256                       // 64 rows per block, 4 waves
#define N4 16777216                           // 268435456 B / 16
#define XST 68                                // staged x row stride (words)
#define TBS 21                                // transpose buffer stride (odd)

typedef float f32x4 __attribute__((ext_vector_type(4)));
typedef double f64x4 __attribute__((ext_vector_type(4)));

// ---------------------------------------------------------------------------
// JAX Threefry-2x32 (partitionable path).  [verified: rounds 1,3,4,5,7,8]
// ---------------------------------------------------------------------------
__device__ __forceinline__ void threefry2x32(uint32_t k0, uint32_t k1,
                                             uint32_t x0, uint32_t x1,
                                             uint32_t& o0, uint32_t& o1) {
  uint32_t ks[3] = {k0, k1, k0 ^ k1 ^ 0x1BD11BDAu};
  x0 += ks[0];
  x1 += ks[1];
  const uint32_t rot[2][4] = {{13u, 15u, 26u, 6u}, {17u, 29u, 16u, 24u}};
#pragma unroll
  for (int i = 0; i < 5; ++i) {
#pragma unroll
    for (int j = 0; j < 4; ++j) {
      uint32_t r = rot[i & 1][j];
      x0 += x1;
      x1 = (x1 << r) | (x1 >> (32u - r));
      x1 ^= x0;
    }
    x0 += ks[(i + 1) % 3];
    x1 += ks[(i + 2) % 3] + (uint32_t)(i + 1);
  }
  o0 = x0;
  o1 = x1;
}

// XLA ErfInv (f32), Giles polynomial — constants bit-match xla math.cc.
__device__ __forceinline__ float erfinv_xla(float x) {
  float w = -log1pf(-x * x);
  float p;
  if (w < 5.0f) {
    w = w - 2.5f;
    p = 2.81022636e-08f;
    p = __fmaf_rn(p, w, 3.43273939e-07f);
    p = __fmaf_rn(p, w, -3.5233877e-06f);
    p = __fmaf_rn(p, w, -4.39150654e-06f);
    p = __fmaf_rn(p, w, 0.00021858087f);
    p = __fmaf_rn(p, w, -0.00125372503f);
    p = __fmaf_rn(p, w, -0.00417768164f);
    p = __fmaf_rn(p, w, 0.246640727f);
    p = __fmaf_rn(p, w, 1.50140941f);
  } else {
    w = sqrtf(w) - 3.0f;
    p = -0.000200214257f;
    p = __fmaf_rn(p, w, 0.000100950558f);
    p = __fmaf_rn(p, w, 0.00134934322f);
    p = __fmaf_rn(p, w, -0.00367342844f);
    p = __fmaf_rn(p, w, 0.00573950773f);
    p = __fmaf_rn(p, w, -0.0076224613f);
    p = __fmaf_rn(p, w, 0.00943887047f);
    p = __fmaf_rn(p, w, 1.00167406f);
    p = __fmaf_rn(p, w, 2.83297682f);
  }
  return p * x;
}

__device__ __forceinline__ float jax_normal(uint32_t idx) {
  uint32_t o0, o1;
  threefry2x32(0u, 42u, 0u, idx, o0, o1);
  uint32_t bits = o0 ^ o1;
  float f = __uint_as_float((bits >> 9) | 0x3f800000u) - 1.0f;  // [0,1)
  const float lo = __uint_as_float(0xBF7FFFFFu);                // -0.99999994
  float v = fmaxf(lo, f * 2.0f + lo);
  return __uint_as_float(0x3FB504F3u) * erfinv_xla(v);  // sqrt(2)_f32 * erfinv
}

// ---------------------------------------------------------------------------
// Fused kernel: 2304 blocks = 256 gate (bid%9==0; 9 coprime 8 -> gates spread
// over all XCDs, round-8 lesson) + 2048 zero.
// LDS = 21.5 KB only (chunk-staging buffer unioned with transpose buffer)
// -> ~7 blocks/CU, so zero blocks keep the HBM store stream saturated
// (round-7 lesson) while gate MFMA work (~13 us total) hides beneath it.
// Gate: x staged per 64-col K-chunk (stride-68 rows: worst 2-way LDS
// aliasing = free); f64 MFMA with runtime-probed D layout [verified r7/r8].
// ---------------------------------------------------------------------------
__global__ __launch_bounds__(256, 4) void fused_kernel(
    const float* __restrict__ x,    // (NROWS, 512)
    const float* __restrict__ Wt,   // (512, 64)
    float* __restrict__ gatesT,     // (NG*NE, GS)
    f32x4* __restrict__ outv) {     // output as f32x4[N4]
  __shared__ float buf[5376];       // 21504 B: x-chunk [64][68] / tb [4][64*21]
  const int bid = blockIdx.x;
  const int role = bid % 9;

  if (role != 0) {
    // ---- zero block ----  [verified round 5]
    const int zid = (bid / 9) * 8 + (role - 1);   // 0..ZERO_BLOCKS-1
    const f32x4 z = {0.f, 0.f, 0.f, 0.f};
    for (int i = zid * 256 + threadIdx.x; i < N4; i += ZERO_BLOCKS * 256)
      __builtin_nontemporal_store(z, &outv[i]);
    return;
  }

  // ---- gate block ----
  const int gid = bid / 9;            // 0..255
  const int tid = threadIdx.x;
  const int l = tid & 63;             // lane
  const int w = tid >> 6;             // wave 0..3
  const int row0b = gid * 64;         // block's first row
  const int row0 = row0b + w * 16;    // wave's first row

  const int i15 = l & 15;             // A row / B-C col position
  const int k4 = l >> 4;              // k-slot within K=4

  // --- runtime probe: which x-row does acc[*][r] hold?  [verified r7/r8]
  f64x4 dr = {0., 0., 0., 0.};
  dr = __builtin_amdgcn_mfma_f64_16x16x4f64((double)i15, 0.25, dr, 0, 0, 0);
  int perm[4];
#pragma unroll
  for (int r = 0; r < 4; ++r) perm[r] = ((int)(dr[r] + 0.5)) & 15;

  // K-loop over 8 chunks of 64 k-values; acc[t] = 16x16 tile, experts 16t..
  f64x4 acc[4] = {{0., 0., 0., 0.}, {0., 0., 0., 0.},
                  {0., 0., 0., 0.}, {0., 0., 0., 0.}};
  const float* xrow = &buf[(w * 16 + i15) * XST + k4];
  for (int ck = 0; ck < 8; ++ck) {
    // stage chunk: 64 rows x 64 cols f32, coalesced f32x4
    for (int i = tid; i < 1024; i += 256) {
      const int r = i >> 4, c = (i & 15) << 2;
      *(f32x4*)&buf[r * XST + c] =
          *(const f32x4*)&x[(size_t)(row0b + r) * DM + (ck << 6) + c];
    }
    __syncthreads();
#pragma unroll
    for (int kkl = 0; kkl < 16; ++kkl) {
      const double a = (double)xrow[kkl * 4];
      const int kk = (ck << 4) + kkl;
      const float* wrow = Wt + ((kk << 2) + k4) * NE + i15;
#pragma unroll
      for (int t = 0; t < 4; ++t) {
        const double b = (double)wrow[16 * t];
        acc[t] = __builtin_amdgcn_mfma_f64_16x16x4f64(a, b, acc[t], 0, 0, 0);
      }
    }
    __syncthreads();
  }

  // noise + fp64 softmax. acc[t][r] = logits[row0+perm[r]][e=16t+i15].
  // 16-lane shfl_xor reduce spans that row's 64 experts (16 lanes x 4 regs).
  float gatef[4][4];  // [t][r]
#pragma unroll
  for (int r = 0; r < 4; ++r) {
    const int row = row0 + perm[r];
    double v[4];
    double m = -1.0e300;
#pragma unroll
    for (int t = 0; t < 4; ++t) {
      const float logit = (float)acc[t][r];
      const float noised =
          logit + 0.015625f * jax_normal((uint32_t)(row * NE + 16 * t + i15));
      v[t] = (double)noised;
      m = fmax(m, v[t]);
    }
#pragma unroll
    for (int off = 1; off < 16; off <<= 1) m = fmax(m, __shfl_xor(m, off, 64));
    double s = 0.0;
#pragma unroll
    for (int t = 0; t < 4; ++t) {
      v[t] = exp(v[t] - m);
      s += v[t];
    }
#pragma unroll
    for (int off = 1; off < 16; off <<= 1) s += __shfl_xor(s, off, 64);
#pragma unroll
    for (int t = 0; t < 4; ++t) gatef[t][r] = (float)(v[t] / s);
  }

  // per-wave LDS transpose (buf reused; x-chunk is dead after barrier above).
  float* tb = buf + w * (NE * TBS);
#pragma unroll
  for (int t = 0; t < 4; ++t)
#pragma unroll
    for (int r = 0; r < 4; ++r)
      tb[(16 * t + i15) * TBS + perm[r]] = gatef[t][r];
  __syncthreads();

  const int g = row0 >> 11;           // group
  const int s0 = row0 & (GS - 1);     // first s of this wave's 16
  float* drow = gatesT + ((size_t)(g * NE + l)) * GS + s0;  // lane l -> expert l
#pragma unroll
  for (int c = 0; c < 4; ++c) {
    f32x4 o;
#pragma unroll
    for (int i = 0; i < 4; ++i) o[i] = tb[l * TBS + 4 * c + i];
    *(f32x4*)&drow[4 * c] = o;
  }
}

// ---------------------------------------------------------------------------
// Topk: one WAVE per (group, expert); 8 coalesced f32x4 loads/lane; top-32
// via per-lane scan + shfl_xor butterfly (max value, min s on ties).
// [verified: rounds 4,5,7,8]
// ---------------------------------------------------------------------------
__global__ __launch_bounds__(64) void topk_kernel(
    const float* __restrict__ gatesT,  // (NG*NE, GS)
    float* __restrict__ out) {         // combine ++ dispatch
  const int ge = blockIdx.x;  // == g*64 + e
  const int g = ge >> 6;
  const int e = ge & 63;
  const int lane = threadIdx.x;

  const float* base = gatesT + (size_t)ge * GS;
  float v[32];
#pragma unroll
  for (int k = 0; k < 8; ++k) {
    const f32x4 t = *(const f32x4*)(base + k * 256 + lane * 4);
#pragma unroll
    for (int i = 0; i < 4; ++i) v[k * 4 + i] = t[i];
  }

  float my_v = 0.0f;
  int my_s = 0;

  for (int c = 0; c < CAP; ++c) {
    float bv = -1.0f;  // gates are strictly positive
    int bj = 0;
#pragma unroll
    for (int j = 0; j < 32; ++j) {
      const bool better = v[j] > bv;
      bv = better ? v[j] : bv;
      bj = better ? j : bj;
    }
    int bs = (bj >> 2) * 256 + lane * 4 + (bj & 3);
#pragma unroll
    for (int off = 1; off < 64; off <<= 1) {
      const float ov = __shfl_xor(bv, off, 64);
      const int os = __shfl_xor(bs, off, 64);
      if (ov > bv || (ov == bv && os < bs)) { bv = ov; bs = os; }
    }
    const bool owner = (lane == ((bs >> 2) & 63));
    const int jj = ((bs >> 8) << 2) | (bs & 3);
#pragma unroll
    for (int j = 0; j < 32; ++j) v[j] = (owner && j == jj) ? -1.0f : v[j];
    if (lane == c) { my_v = bv; my_s = bs; }
  }

  float* combine = out;                   // (G,S,E,C)
  float* dispatch = out + COMBINE_ELEMS;  // (G,E,C,S)
  if (lane < CAP) {
    combine[(((size_t)(g * GS + my_s)) * NE + e) * CAP + lane] = my_v;
    dispatch[(((size_t)(g * NE + e)) * CAP + lane) * GS + my_s] = 1.0f;
  }
}

extern "C" void kernel_launch(void* const* d_in, const int* in_sizes, int n_in,
                              void* d_out, int out_size, void* d_ws,
                              size_t ws_size, hipStream_t stream) {
  (void)in_sizes; (void)n_in; (void)ws_size; (void)out_size;
  const float* x = (const float*)d_in[0];   // (8,2048,512) f32
  const float* Wt = (const float*)d_in[1];  // (512,64) f32
  float* out = (float*)d_out;
  float* gatesT = (float*)d_ws;             // (512, 2048) f32 = 4 MB scratch

  fused_kernel<<<GATE_BLOCKS * 9, 256, 0, stream>>>(x, Wt, gatesT, (f32x4*)out);
  topk_kernel<<<NG * NE, 64, 0, stream>>>(gatesT, out);
}

// Round 10
// 160.448 us; speedup vs baseline: 3.2163x; 1.0793x over previous
//
#include <hip/hip_runtime.h>
#include <math.h>
#include <stdint.h>

#define NG 8
#define GS 2048
#define DM 512
#define NE 64
#define CAP 32
#define NROWS (NG * GS)                       // 16384 total rows (g,s)
#define COMBINE_ELEMS (33554432ull)           // 8*2048*64*32

#define GATE_BLOCKS 256                       // 64 rows per block, 4 waves
#define N4 16777216                           // 268435456 B / 16
#define XST 68                                // staged x row stride (words)
#define TBS 21                                // transpose buffer stride (odd)

typedef float f32x4 __attribute__((ext_vector_type(4)));
typedef double f64x4 __attribute__((ext_vector_type(4)));

// ---------------------------------------------------------------------------
// JAX Threefry-2x32 (partitionable path).  [verified: rounds 1,3,4,5,7,8,9]
// ---------------------------------------------------------------------------
__device__ __forceinline__ void threefry2x32(uint32_t k0, uint32_t k1,
                                             uint32_t x0, uint32_t x1,
                                             uint32_t& o0, uint32_t& o1) {
  uint32_t ks[3] = {k0, k1, k0 ^ k1 ^ 0x1BD11BDAu};
  x0 += ks[0];
  x1 += ks[1];
  const uint32_t rot[2][4] = {{13u, 15u, 26u, 6u}, {17u, 29u, 16u, 24u}};
#pragma unroll
  for (int i = 0; i < 5; ++i) {
#pragma unroll
    for (int j = 0; j < 4; ++j) {
      uint32_t r = rot[i & 1][j];
      x0 += x1;
      x1 = (x1 << r) | (x1 >> (32u - r));
      x1 ^= x0;
    }
    x0 += ks[(i + 1) % 3];
    x1 += ks[(i + 2) % 3] + (uint32_t)(i + 1);
  }
  o0 = x0;
  o1 = x1;
}

// XLA ErfInv (f32), Giles polynomial — constants bit-match xla math.cc.
__device__ __forceinline__ float erfinv_xla(float x) {
  float w = -log1pf(-x * x);
  float p;
  if (w < 5.0f) {
    w = w - 2.5f;
    p = 2.81022636e-08f;
    p = __fmaf_rn(p, w, 3.43273939e-07f);
    p = __fmaf_rn(p, w, -3.5233877e-06f);
    p = __fmaf_rn(p, w, -4.39150654e-06f);
    p = __fmaf_rn(p, w, 0.00021858087f);
    p = __fmaf_rn(p, w, -0.00125372503f);
    p = __fmaf_rn(p, w, -0.00417768164f);
    p = __fmaf_rn(p, w, 0.246640727f);
    p = __fmaf_rn(p, w, 1.50140941f);
  } else {
    w = sqrtf(w) - 3.0f;
    p = -0.000200214257f;
    p = __fmaf_rn(p, w, 0.000100950558f);
    p = __fmaf_rn(p, w, 0.00134934322f);
    p = __fmaf_rn(p, w, -0.00367342844f);
    p = __fmaf_rn(p, w, 0.00573950773f);
    p = __fmaf_rn(p, w, -0.0076224613f);
    p = __fmaf_rn(p, w, 0.00943887047f);
    p = __fmaf_rn(p, w, 1.00167406f);
    p = __fmaf_rn(p, w, 2.83297682f);
  }
  return p * x;
}

__device__ __forceinline__ float jax_normal(uint32_t idx) {
  uint32_t o0, o1;
  threefry2x32(0u, 42u, 0u, idx, o0, o1);
  uint32_t bits = o0 ^ o1;
  float f = __uint_as_float((bits >> 9) | 0x3f800000u) - 1.0f;  // [0,1)
  const float lo = __uint_as_float(0xBF7FFFFFu);                // -0.99999994
  float v = fmaxf(lo, f * 2.0f + lo);
  return __uint_as_float(0x3FB504F3u) * erfinv_xla(v);  // sqrt(2)_f32 * erfinv
}

// ---------------------------------------------------------------------------
// Kernel 0: zero the 256 MB output. EXACT round-3 configuration (4096 blocks,
// nontemporal f32x4, grid-stride) — inferred ~41 us standalone. This round
// exists to MEASURE it in its own rocprof row (un-fused; round-9 lesson:
// fused zero stream ran at 1.86 TB/s for reasons no fusion variant fixed).
// ---------------------------------------------------------------------------
__global__ __launch_bounds__(256) void zero_kernel(f32x4* __restrict__ p, int n4) {
  int i = blockIdx.x * blockDim.x + threadIdx.x;
  const int stride = gridDim.x * blockDim.x;
  const f32x4 z = {0.f, 0.f, 0.f, 0.f};
  for (; i < n4; i += stride) __builtin_nontemporal_store(z, &p[i]);
}

// ---------------------------------------------------------------------------
// Kernel 1: gate, standalone (round-9 internals, fusion wrapper removed).
// 256 blocks x 4 waves; per wave one 16-row x 64-expert tile via
// v_mfma_f64_16x16x4_f64 with runtime-probed D layout [verified r7/r8/r9].
// x staged per 64-col K-chunk (stride-68 rows -> worst 2-way aliasing).
// ---------------------------------------------------------------------------
__global__ __launch_bounds__(256) void gate_kernel(
    const float* __restrict__ x,    // (NROWS, 512)
    const float* __restrict__ Wt,   // (512, 64)
    float* __restrict__ gatesT) {   // (NG*NE, GS)
  __shared__ float buf[5376];       // 21504 B: x-chunk [64][68] / tb [4][64*21]
  const int gid = blockIdx.x;         // 0..255
  const int tid = threadIdx.x;
  const int l = tid & 63;             // lane
  const int w = tid >> 6;             // wave 0..3
  const int row0b = gid * 64;         // block's first row
  const int row0 = row0b + w * 16;    // wave's first row

  const int i15 = l & 15;             // A row / B-C col position
  const int k4 = l >> 4;              // k-slot within K=4

  // --- runtime probe: which x-row does acc[*][r] hold?  [verified r7/r8/r9]
  f64x4 dr = {0., 0., 0., 0.};
  dr = __builtin_amdgcn_mfma_f64_16x16x4f64((double)i15, 0.25, dr, 0, 0, 0);
  int perm[4];
#pragma unroll
  for (int r = 0; r < 4; ++r) perm[r] = ((int)(dr[r] + 0.5)) & 15;

  // K-loop over 8 chunks of 64 k-values; acc[t] = 16x16 tile, experts 16t..
  f64x4 acc[4] = {{0., 0., 0., 0.}, {0., 0., 0., 0.},
                  {0., 0., 0., 0.}, {0., 0., 0., 0.}};
  const float* xrow = &buf[(w * 16 + i15) * XST + k4];
  for (int ck = 0; ck < 8; ++ck) {
    // stage chunk: 64 rows x 64 cols f32, coalesced f32x4
    for (int i = tid; i < 1024; i += 256) {
      const int r = i >> 4, c = (i & 15) << 2;
      *(f32x4*)&buf[r * XST + c] =
          *(const f32x4*)&x[(size_t)(row0b + r) * DM + (ck << 6) + c];
    }
    __syncthreads();
#pragma unroll
    for (int kkl = 0; kkl < 16; ++kkl) {
      const double a = (double)xrow[kkl * 4];
      const int kk = (ck << 4) + kkl;
      const float* wrow = Wt + ((kk << 2) + k4) * NE + i15;
#pragma unroll
      for (int t = 0; t < 4; ++t) {
        const double b = (double)wrow[16 * t];
        acc[t] = __builtin_amdgcn_mfma_f64_16x16x4f64(a, b, acc[t], 0, 0, 0);
      }
    }
    __syncthreads();
  }

  // noise + fp64 softmax. acc[t][r] = logits[row0+perm[r]][e=16t+i15].
  float gatef[4][4];  // [t][r]
#pragma unroll
  for (int r = 0; r < 4; ++r) {
    const int row = row0 + perm[r];
    double v[4];
    double m = -1.0e300;
#pragma unroll
    for (int t = 0; t < 4; ++t) {
      const float logit = (float)acc[t][r];
      const float noised =
          logit + 0.015625f * jax_normal((uint32_t)(row * NE + 16 * t + i15));
      v[t] = (double)noised;
      m = fmax(m, v[t]);
    }
#pragma unroll
    for (int off = 1; off < 16; off <<= 1) m = fmax(m, __shfl_xor(m, off, 64));
    double s = 0.0;
#pragma unroll
    for (int t = 0; t < 4; ++t) {
      v[t] = exp(v[t] - m);
      s += v[t];
    }
#pragma unroll
    for (int off = 1; off < 16; off <<= 1) s += __shfl_xor(s, off, 64);
#pragma unroll
    for (int t = 0; t < 4; ++t) gatef[t][r] = (float)(v[t] / s);
  }

  // per-wave LDS transpose (buf reused; x-chunk dead after barrier above).
  float* tb = buf + w * (NE * TBS);
#pragma unroll
  for (int t = 0; t < 4; ++t)
#pragma unroll
    for (int r = 0; r < 4; ++r)
      tb[(16 * t + i15) * TBS + perm[r]] = gatef[t][r];
  __syncthreads();

  const int g = row0 >> 11;           // group
  const int s0 = row0 & (GS - 1);     // first s of this wave's 16
  float* drow = gatesT + ((size_t)(g * NE + l)) * GS + s0;  // lane l -> expert l
#pragma unroll
  for (int c = 0; c < 4; ++c) {
    f32x4 o;
#pragma unroll
    for (int i = 0; i < 4; ++i) o[i] = tb[l * TBS + 4 * c + i];
    *(f32x4*)&drow[4 * c] = o;
  }
}

// ---------------------------------------------------------------------------
// Kernel 2: topk — one WAVE per (group, expert); 8 coalesced f32x4 loads/lane;
// top-32 via per-lane scan + shfl_xor butterfly (max value, min s on ties).
// [verified: rounds 4,5,7,8,9]
// ---------------------------------------------------------------------------
__global__ __launch_bounds__(64) void topk_kernel(
    const float* __restrict__ gatesT,  // (NG*NE, GS)
    float* __restrict__ out) {         // combine ++ dispatch
  const int ge = blockIdx.x;  // == g*64 + e
  const int g = ge >> 6;
  const int e = ge & 63;
  const int lane = threadIdx.x;

  const float* base = gatesT + (size_t)ge * GS;
  float v[32];
#pragma unroll
  for (int k = 0; k < 8; ++k) {
    const f32x4 t = *(const f32x4*)(base + k * 256 + lane * 4);
#pragma unroll
    for (int i = 0; i < 4; ++i) v[k * 4 + i] = t[i];
  }

  float my_v = 0.0f;
  int my_s = 0;

  for (int c = 0; c < CAP; ++c) {
    float bv = -1.0f;  // gates are strictly positive
    int bj = 0;
#pragma unroll
    for (int j = 0; j < 32; ++j) {
      const bool better = v[j] > bv;
      bv = better ? v[j] : bv;
      bj = better ? j : bj;
    }
    int bs = (bj >> 2) * 256 + lane * 4 + (bj & 3);
#pragma unroll
    for (int off = 1; off < 64; off <<= 1) {
      const float ov = __shfl_xor(bv, off, 64);
      const int os = __shfl_xor(bs, off, 64);
      if (ov > bv || (ov == bv && os < bs)) { bv = ov; bs = os; }
    }
    const bool owner = (lane == ((bs >> 2) & 63));
    const int jj = ((bs >> 8) << 2) | (bs & 3);
#pragma unroll
    for (int j = 0; j < 32; ++j) v[j] = (owner && j == jj) ? -1.0f : v[j];
    if (lane == c) { my_v = bv; my_s = bs; }
  }

  float* combine = out;                   // (G,S,E,C)
  float* dispatch = out + COMBINE_ELEMS;  // (G,E,C,S)
  if (lane < CAP) {
    combine[(((size_t)(g * GS + my_s)) * NE + e) * CAP + lane] = my_v;
    dispatch[(((size_t)(g * NE + e)) * CAP + lane) * GS + my_s] = 1.0f;
  }
}

extern "C" void kernel_launch(void* const* d_in, const int* in_sizes, int n_in,
                              void* d_out, int out_size, void* d_ws,
                              size_t ws_size, hipStream_t stream) {
  (void)in_sizes; (void)n_in; (void)ws_size;
  const float* x = (const float*)d_in[0];   // (8,2048,512) f32
  const float* Wt = (const float*)d_in[1];  // (512,64) f32
  float* out = (float*)d_out;
  float* gatesT = (float*)d_ws;             // (512, 2048) f32 = 4 MB scratch

  int n4 = out_size / 4;
  zero_kernel<<<4096, 256, 0, stream>>>((f32x4*)out, n4);
  gate_kernel<<<GATE_BLOCKS, 256, 0, stream>>>(x, Wt, gatesT);
  topk_kernel<<<NG * NE, 64, 0, stream>>>(gatesT, out);
}

// Round 11
// 140.006 us; speedup vs baseline: 3.6859x; 1.1460x over previous
//
#include <hip/hip_runtime.h>
#include <math.h>
#include <stdint.h>

#define NG 8
#define GS 2048
#define DM 512
#define NE 64
#define CAP 32
#define NROWS (NG * GS)                       // 16384 total rows (g,s)
#define COMBINE_ELEMS (33554432ull)           // 8*2048*64*32

#define GATE_BLOCKS 256                       // 64 rows per block, 4 waves
#define N4 16777216                           // 268435456 B / 16
#define XST 68                                // staged x row stride (words)
#define TBS 21                                // transpose buffer stride (odd)

typedef float f32x4 __attribute__((ext_vector_type(4)));
typedef double f64x4 __attribute__((ext_vector_type(4)));

// ---------------------------------------------------------------------------
// JAX Threefry-2x32 (partitionable path).  [verified: rounds 1,3,4,5,7,8,9,10]
// ---------------------------------------------------------------------------
__device__ __forceinline__ void threefry2x32(uint32_t k0, uint32_t k1,
                                             uint32_t x0, uint32_t x1,
                                             uint32_t& o0, uint32_t& o1) {
  uint32_t ks[3] = {k0, k1, k0 ^ k1 ^ 0x1BD11BDAu};
  x0 += ks[0];
  x1 += ks[1];
  const uint32_t rot[2][4] = {{13u, 15u, 26u, 6u}, {17u, 29u, 16u, 24u}};
#pragma unroll
  for (int i = 0; i < 5; ++i) {
#pragma unroll
    for (int j = 0; j < 4; ++j) {
      uint32_t r = rot[i & 1][j];
      x0 += x1;
      x1 = (x1 << r) | (x1 >> (32u - r));
      x1 ^= x0;
    }
    x0 += ks[(i + 1) % 3];
    x1 += ks[(i + 2) % 3] + (uint32_t)(i + 1);
  }
  o0 = x0;
  o1 = x1;
}

// XLA ErfInv (f32), Giles polynomial — constants bit-match xla math.cc.
__device__ __forceinline__ float erfinv_xla(float x) {
  float w = -log1pf(-x * x);
  float p;
  if (w < 5.0f) {
    w = w - 2.5f;
    p = 2.81022636e-08f;
    p = __fmaf_rn(p, w, 3.43273939e-07f);
    p = __fmaf_rn(p, w, -3.5233877e-06f);
    p = __fmaf_rn(p, w, -4.39150654e-06f);
    p = __fmaf_rn(p, w, 0.00021858087f);
    p = __fmaf_rn(p, w, -0.00125372503f);
    p = __fmaf_rn(p, w, -0.00417768164f);
    p = __fmaf_rn(p, w, 0.246640727f);
    p = __fmaf_rn(p, w, 1.50140941f);
  } else {
    w = sqrtf(w) - 3.0f;
    p = -0.000200214257f;
    p = __fmaf_rn(p, w, 0.000100950558f);
    p = __fmaf_rn(p, w, 0.00134934322f);
    p = __fmaf_rn(p, w, -0.00367342844f);
    p = __fmaf_rn(p, w, 0.00573950773f);
    p = __fmaf_rn(p, w, -0.0076224613f);
    p = __fmaf_rn(p, w, 0.00943887047f);
    p = __fmaf_rn(p, w, 1.00167406f);
    p = __fmaf_rn(p, w, 2.83297682f);
  }
  return p * x;
}

__device__ __forceinline__ float jax_normal(uint32_t idx) {
  uint32_t o0, o1;
  threefry2x32(0u, 42u, 0u, idx, o0, o1);
  uint32_t bits = o0 ^ o1;
  float f = __uint_as_float((bits >> 9) | 0x3f800000u) - 1.0f;  // [0,1)
  const float lo = __uint_as_float(0xBF7FFFFFu);                // -0.99999994
  float v = fmaxf(lo, f * 2.0f + lo);
  return __uint_as_float(0x3FB504F3u) * erfinv_xla(v);  // sqrt(2)_f32 * erfinv
}

// ---------------------------------------------------------------------------
// Kernel 0: zero the 256 MB output. ROUND-11 CHANGE (the only one): PLAIN
// f32x4 stores (no nontemporal — theory: `nt` bypasses L2 write-aggregation,
// posting 16B partial-line HBM writes -> RMW -> ~2.1 TB/s, the whale of
// rounds 1-10). Exact partition like fillBufferAligned: 16384 blocks x 16 KB,
// 4 coalesced full-wave stores per thread, no loop-carried overhead.
// ---------------------------------------------------------------------------
__global__ __launch_bounds__(256) void zero_kernel(f32x4* __restrict__ p) {
  const int b = blockIdx.x * 1024 + threadIdx.x;  // f32x4 units
  const f32x4 z = {0.f, 0.f, 0.f, 0.f};
#pragma unroll
  for (int j = 0; j < 4; ++j) p[b + j * 256] = z;
}

// ---------------------------------------------------------------------------
// Kernel 1: gate — BYTE-IDENTICAL to round 10 (verified absmax 4.8828e-4).
// 256 blocks x 4 waves; per wave one 16-row x 64-expert tile via
// v_mfma_f64_16x16x4_f64 with runtime-probed D layout [verified r7-r10].
// ---------------------------------------------------------------------------
__global__ __launch_bounds__(256) void gate_kernel(
    const float* __restrict__ x,    // (NROWS, 512)
    const float* __restrict__ Wt,   // (512, 64)
    float* __restrict__ gatesT) {   // (NG*NE, GS)
  __shared__ float buf[5376];       // 21504 B: x-chunk [64][68] / tb [4][64*21]
  const int gid = blockIdx.x;         // 0..255
  const int tid = threadIdx.x;
  const int l = tid & 63;             // lane
  const int w = tid >> 6;             // wave 0..3
  const int row0b = gid * 64;         // block's first row
  const int row0 = row0b + w * 16;    // wave's first row

  const int i15 = l & 15;             // A row / B-C col position
  const int k4 = l >> 4;              // k-slot within K=4

  // --- runtime probe: which x-row does acc[*][r] hold?  [verified r7-r10]
  f64x4 dr = {0., 0., 0., 0.};
  dr = __builtin_amdgcn_mfma_f64_16x16x4f64((double)i15, 0.25, dr, 0, 0, 0);
  int perm[4];
#pragma unroll
  for (int r = 0; r < 4; ++r) perm[r] = ((int)(dr[r] + 0.5)) & 15;

  // K-loop over 8 chunks of 64 k-values; acc[t] = 16x16 tile, experts 16t..
  f64x4 acc[4] = {{0., 0., 0., 0.}, {0., 0., 0., 0.},
                  {0., 0., 0., 0.}, {0., 0., 0., 0.}};
  const float* xrow = &buf[(w * 16 + i15) * XST + k4];
  for (int ck = 0; ck < 8; ++ck) {
    // stage chunk: 64 rows x 64 cols f32, coalesced f32x4
    for (int i = tid; i < 1024; i += 256) {
      const int r = i >> 4, c = (i & 15) << 2;
      *(f32x4*)&buf[r * XST + c] =
          *(const f32x4*)&x[(size_t)(row0b + r) * DM + (ck << 6) + c];
    }
    __syncthreads();
#pragma unroll
    for (int kkl = 0; kkl < 16; ++kkl) {
      const double a = (double)xrow[kkl * 4];
      const int kk = (ck << 4) + kkl;
      const float* wrow = Wt + ((kk << 2) + k4) * NE + i15;
#pragma unroll
      for (int t = 0; t < 4; ++t) {
        const double b = (double)wrow[16 * t];
        acc[t] = __builtin_amdgcn_mfma_f64_16x16x4f64(a, b, acc[t], 0, 0, 0);
      }
    }
    __syncthreads();
  }

  // noise + fp64 softmax. acc[t][r] = logits[row0+perm[r]][e=16t+i15].
  float gatef[4][4];  // [t][r]
#pragma unroll
  for (int r = 0; r < 4; ++r) {
    const int row = row0 + perm[r];
    double v[4];
    double m = -1.0e300;
#pragma unroll
    for (int t = 0; t < 4; ++t) {
      const float logit = (float)acc[t][r];
      const float noised =
          logit + 0.015625f * jax_normal((uint32_t)(row * NE + 16 * t + i15));
      v[t] = (double)noised;
      m = fmax(m, v[t]);
    }
#pragma unroll
    for (int off = 1; off < 16; off <<= 1) m = fmax(m, __shfl_xor(m, off, 64));
    double s = 0.0;
#pragma unroll
    for (int t = 0; t < 4; ++t) {
      v[t] = exp(v[t] - m);
      s += v[t];
    }
#pragma unroll
    for (int off = 1; off < 16; off <<= 1) s += __shfl_xor(s, off, 64);
#pragma unroll
    for (int t = 0; t < 4; ++t) gatef[t][r] = (float)(v[t] / s);
  }

  // per-wave LDS transpose (buf reused; x-chunk dead after barrier above).
  float* tb = buf + w * (NE * TBS);
#pragma unroll
  for (int t = 0; t < 4; ++t)
#pragma unroll
    for (int r = 0; r < 4; ++r)
      tb[(16 * t + i15) * TBS + perm[r]] = gatef[t][r];
  __syncthreads();

  const int g = row0 >> 11;           // group
  const int s0 = row0 & (GS - 1);     // first s of this wave's 16
  float* drow = gatesT + ((size_t)(g * NE + l)) * GS + s0;  // lane l -> expert l
#pragma unroll
  for (int c = 0; c < 4; ++c) {
    f32x4 o;
#pragma unroll
    for (int i = 0; i < 4; ++i) o[i] = tb[l * TBS + 4 * c + i];
    *(f32x4*)&drow[4 * c] = o;
  }
}

// ---------------------------------------------------------------------------
// Kernel 2: topk — BYTE-IDENTICAL to round 10.  [verified: rounds 4,5,7-10]
// ---------------------------------------------------------------------------
__global__ __launch_bounds__(64) void topk_kernel(
    const float* __restrict__ gatesT,  // (NG*NE, GS)
    float* __restrict__ out) {         // combine ++ dispatch
  const int ge = blockIdx.x;  // == g*64 + e
  const int g = ge >> 6;
  const int e = ge & 63;
  const int lane = threadIdx.x;

  const float* base = gatesT + (size_t)ge * GS;
  float v[32];
#pragma unroll
  for (int k = 0; k < 8; ++k) {
    const f32x4 t = *(const f32x4*)(base + k * 256 + lane * 4);
#pragma unroll
    for (int i = 0; i < 4; ++i) v[k * 4 + i] = t[i];
  }

  float my_v = 0.0f;
  int my_s = 0;

  for (int c = 0; c < CAP; ++c) {
    float bv = -1.0f;  // gates are strictly positive
    int bj = 0;
#pragma unroll
    for (int j = 0; j < 32; ++j) {
      const bool better = v[j] > bv;
      bv = better ? v[j] : bv;
      bj = better ? j : bj;
    }
    int bs = (bj >> 2) * 256 + lane * 4 + (bj & 3);
#pragma unroll
    for (int off = 1; off < 64; off <<= 1) {
      const float ov = __shfl_xor(bv, off, 64);
      const int os = __shfl_xor(bs, off, 64);
      if (ov > bv || (ov == bv && os < bs)) { bv = ov; bs = os; }
    }
    const bool owner = (lane == ((bs >> 2) & 63));
    const int jj = ((bs >> 8) << 2) | (bs & 3);
#pragma unroll
    for (int j = 0; j < 32; ++j) v[j] = (owner && j == jj) ? -1.0f : v[j];
    if (lane == c) { my_v = bv; my_s = bs; }
  }

  float* combine = out;                   // (G,S,E,C)
  float* dispatch = out + COMBINE_ELEMS;  // (G,E,C,S)
  if (lane < CAP) {
    combine[(((size_t)(g * GS + my_s)) * NE + e) * CAP + lane] = my_v;
    dispatch[(((size_t)(g * NE + e)) * CAP + lane) * GS + my_s] = 1.0f;
  }
}

extern "C" void kernel_launch(void* const* d_in, const int* in_sizes, int n_in,
                              void* d_out, int out_size, void* d_ws,
                              size_t ws_size, hipStream_t stream) {
  (void)in_sizes; (void)n_in; (void)ws_size; (void)out_size;
  const float* x = (const float*)d_in[0];   // (8,2048,512) f32
  const float* Wt = (const float*)d_in[1];  // (512,64) f32
  float* out = (float*)d_out;
  float* gatesT = (float*)d_ws;             // (512, 2048) f32 = 4 MB scratch

  zero_kernel<<<N4 / 1024, 256, 0, stream>>>((f32x4*)out);
  gate_kernel<<<GATE_BLOCKS, 256, 0, stream>>>(x, Wt, gatesT);
  topk_kernel<<<NG * NE, 64, 0, stream>>>(gatesT, out);
}